// Round 1
// baseline (253.651 us; speedup 1.0000x reference)
//
#include <hip/hip_runtime.h>
#include <stdint.h>

#define B_N 1024
#define K_N 64
#define O_N 4096
#define I_N 4096

// ---------------------------------------------------------------------------
// Transpose W (O x I) -> WT (I x O), 64x64 tiles, LDS padded +1.
// ---------------------------------------------------------------------------
__global__ __launch_bounds__(256) void transpose_kernel(
    const float* __restrict__ W, float* __restrict__ WT) {
  __shared__ float tile[64][65];
  const int tx = threadIdx.x;  // 0..63
  const int ty = threadIdx.y;  // 0..3
  const int i0 = blockIdx.x * 64;
  const int o0 = blockIdx.y * 64;
#pragma unroll
  for (int r = 0; r < 16; ++r) {
    int o = ty + r * 4;
    tile[o][tx] = W[(size_t)(o0 + o) * I_N + i0 + tx];
  }
  __syncthreads();
#pragma unroll
  for (int r = 0; r < 16; ++r) {
    int i = ty + r * 4;
    WT[(size_t)(i0 + i) * O_N + o0 + tx] = tile[tx][i];
  }
}

// ---------------------------------------------------------------------------
// Per-sample gather-matvec (bit-exact vs np: fp32, ascending-k, unfused
// mul/add, bias added last) + fused exact top-64 (radix select + 64-lane
// bitonic, ties -> lower index first).
// ---------------------------------------------------------------------------
template <bool TRANSPOSED>
__global__ __launch_bounds__(256) void selgemv_topk(
    const float* __restrict__ x,     // B x K
    const float* __restrict__ Wsrc,  // TRANSPOSED ? WT (I x O) : W (O x I)
    const float* __restrict__ bias,  // O
    const int* __restrict__ idx,     // B x K (int32)
    float* __restrict__ out)         // [B*K values][B*K indices-as-float]
{
  __shared__ float sx[K_N];
  __shared__ int si[K_N];
  __shared__ float svals[O_N];
  __shared__ unsigned int hist[256];
  __shared__ unsigned int scan[256];
  __shared__ unsigned int sel_u[64];
  __shared__ int sel_i[64];
  __shared__ int eqlist[128];
  __shared__ unsigned int s_T, s_ngt, s_cntgt, s_cnteq;
  __shared__ unsigned int s_remaining, s_prefix;

  const int t = threadIdx.x;   // 0..255
  const int b = blockIdx.x;    // 0..1023

  if (t < K_N) {
    sx[t] = x[b * K_N + t];
    si[t] = idx[b * K_N + t];
  }
  if (t == 0) {
    s_remaining = 64u;
    s_prefix = 0u;
    s_cntgt = 0u;
    s_cnteq = 0u;
  }
  __syncthreads();

  // ---- gather matvec: thread t owns 16 outputs as 4 float4 groups,
  //      o = (j*256 + t)*4 + c  (coalesced across the wave) ----
  float acc[16];
#pragma unroll
  for (int j = 0; j < 16; ++j) acc[j] = 0.0f;

  for (int k = 0; k < K_N; ++k) {
    const float xk = sx[k];
    const int ik = si[k];
    if (TRANSPOSED) {
      const float4* row = (const float4*)(Wsrc + (size_t)ik * O_N);
#pragma unroll
      for (int j = 0; j < 4; ++j) {
        float4 w = row[j * 256 + t];
        acc[4 * j + 0] = __fadd_rn(acc[4 * j + 0], __fmul_rn(xk, w.x));
        acc[4 * j + 1] = __fadd_rn(acc[4 * j + 1], __fmul_rn(xk, w.y));
        acc[4 * j + 2] = __fadd_rn(acc[4 * j + 2], __fmul_rn(xk, w.z));
        acc[4 * j + 3] = __fadd_rn(acc[4 * j + 3], __fmul_rn(xk, w.w));
      }
    } else {
#pragma unroll
      for (int j = 0; j < 4; ++j) {
        int o0 = (j * 256 + t) * 4;
#pragma unroll
        for (int c = 0; c < 4; ++c) {
          float w = Wsrc[(size_t)(o0 + c) * I_N + ik];
          acc[4 * j + c] = __fadd_rn(acc[4 * j + c], __fmul_rn(xk, w));
        }
      }
    }
  }

  // bias (added last, matching np), stash to LDS
#pragma unroll
  for (int j = 0; j < 4; ++j) {
    int g = j * 256 + t;
    float4 bb = ((const float4*)bias)[g];
    float4 r;
    r.x = __fadd_rn(acc[4 * j + 0], bb.x);
    r.y = __fadd_rn(acc[4 * j + 1], bb.y);
    r.z = __fadd_rn(acc[4 * j + 2], bb.z);
    r.w = __fadd_rn(acc[4 * j + 3], bb.w);
    ((float4*)svals)[g] = r;
  }
  __syncthreads();

  // ---- monotone key map: descending float == descending uint ----
  unsigned int myu[16];
#pragma unroll
  for (int j = 0; j < 16; ++j) {
    float f = svals[t + 256 * j];
    unsigned int s = __float_as_uint(f);
    myu[j] = (s & 0x80000000u) ? ~s : (s | 0x80000000u);
  }

  // ---- 4-round radix select (8 bits/round, top-down) ----
  for (int round = 3; round >= 0; --round) {
    const int shift = round * 8;
    hist[t] = 0u;
    __syncthreads();
    const unsigned int pfx = s_prefix;
    const unsigned int rem = s_remaining;
    const unsigned int himask =
        (round == 3) ? 0u : (0xFFFFFFFFu << (shift + 8));
#pragma unroll
    for (int j = 0; j < 16; ++j) {
      if ((myu[j] & himask) == (pfx & himask))
        atomicAdd(&hist[(myu[j] >> shift) & 255u], 1u);
    }
    __syncthreads();
    scan[t] = hist[t];
    __syncthreads();
    // inclusive suffix-sum over 256 bins (Hillis-Steele, read-then-write)
    for (int off = 1; off < 256; off <<= 1) {
      unsigned int v = (t + off < 256) ? scan[t + off] : 0u;
      __syncthreads();
      scan[t] += v;
      __syncthreads();
    }
    const unsigned int c_ge = scan[t];
    const unsigned int c_gt = (t < 255) ? scan[t + 1] : 0u;
    if (c_ge >= rem && c_gt < rem) {  // unique crossing (scan monotone)
      s_T = (unsigned int)t;
      s_ngt = c_gt;
    }
    __syncthreads();
    if (t == 0) {
      s_prefix |= (s_T << shift);
      s_remaining -= s_ngt;
    }
    __syncthreads();
  }
  const unsigned int ustar = s_prefix;

  // ---- compact winners (u > u*) and boundary ties (u == u*) ----
#pragma unroll
  for (int j = 0; j < 16; ++j) {
    const unsigned int u = myu[j];
    if (u > ustar) {
      unsigned int p = atomicAdd(&s_cntgt, 1u);
      sel_u[p] = u;
      sel_i[p] = t + 256 * j;
    } else if (u == ustar) {
      unsigned int p = atomicAdd(&s_cnteq, 1u);
      if (p < 128u) eqlist[p] = t + 256 * j;
    }
  }
  __syncthreads();

  // rare path: >1 boundary tie -> need smallest indices first
  if (t == 0 && s_cnteq > 1u) {
    int n = (int)(s_cnteq < 128u ? s_cnteq : 128u);
    for (int a = 1; a < n; ++a) {
      int v = eqlist[a];
      int c = a;
      while (c > 0 && eqlist[c - 1] > v) {
        eqlist[c] = eqlist[c - 1];
        --c;
      }
      eqlist[c] = v;
    }
  }
  __syncthreads();

  // ---- wave-0 bitonic sort of exactly 64 entries ----
  if (t < 64) {
    const int n_gt = (int)s_cntgt;  // < 64 by construction
    unsigned int u;
    int oi;
    if (t < n_gt) {
      u = sel_u[t];
      oi = sel_i[t];
    } else {
      u = ustar;
      oi = eqlist[t - n_gt];
    }
    // ascending sort of (~u, idx): value descending, index ascending on ties
    unsigned long long key =
        ((unsigned long long)(~u) << 32) | (unsigned int)oi;
    for (int kk = 2; kk <= 64; kk <<= 1) {
      for (int jj = kk >> 1; jj > 0; jj >>= 1) {
        unsigned long long partner = __shfl_xor(key, jj, 64);
        const bool up = ((t & kk) == 0);
        const bool lower = ((t & jj) == 0);
        unsigned long long mn = key < partner ? key : partner;
        unsigned long long mx = key < partner ? partner : key;
        key = (up == lower) ? mn : mx;
      }
    }
    const unsigned int su = ~(unsigned int)(key >> 32);
    const int so = (int)(key & 0xFFFFFFFFu);
    const float f = (su & 0x80000000u) ? __uint_as_float(su ^ 0x80000000u)
                                       : __uint_as_float(~su);
    out[b * 64 + t] = f;                         // values
    out[B_N * 64 + b * 64 + t] = (float)so;      // indices (exact in fp32)
  }
}

extern "C" void kernel_launch(void* const* d_in, const int* in_sizes, int n_in,
                              void* d_out, int out_size, void* d_ws,
                              size_t ws_size, hipStream_t stream) {
  const float* x = (const float*)d_in[0];     // (1024, 64)
  const float* W = (const float*)d_in[1];     // (4096, 4096)
  const float* bias = (const float*)d_in[2];  // (4096,)
  const int* idx = (const int*)d_in[3];       // (1024, 64) int32
  float* out = (float*)d_out;                 // 2 * 1024 * 64 floats

  const size_t wt_bytes = (size_t)I_N * O_N * sizeof(float);  // 64 MB
  if (ws_size >= wt_bytes) {
    float* WT = (float*)d_ws;
    transpose_kernel<<<dim3(I_N / 64, O_N / 64), dim3(64, 4), 0, stream>>>(W,
                                                                           WT);
    selgemv_topk<true><<<B_N, 256, 0, stream>>>(x, WT, bias, idx, out);
  } else {
    selgemv_topk<false><<<B_N, 256, 0, stream>>>(x, W, bias, idx, out);
  }
}